// Round 6
// baseline (11.422 us; speedup 1.0000x reference)
//
#include <hip/hip_runtime.h>

#define NB   16384
#define HID  32
#define NR   32             // table rows (uf), 31 intervals
#define NC   64             // table cols (u),  63 intervals
#define L2E  1.44269504f    // log2(e)
#define LN2  0.69314718f

// softplus via native base-2 exp/log
__device__ __forceinline__ float softplus_fast(float x) {
    return LN2 * __builtin_amdgcn_logf(1.0f + __builtin_amdgcn_exp2f(x * L2E));
}

// One dispatch. Each block builds a 32(uf) x 64(u) normalized-CDF table in LDS
// (8 rows per wave, interleaved through one h-loop: 16 trans ops in flight),
// then serves 128 bilinear lookups. 256 blocks -> all CUs active.
__global__ __launch_bounds__(256) void marg_kernel(
    const float* __restrict__ U,  const float* __restrict__ W1,
    const float* __restrict__ b1, const float* __restrict__ W2,
    const float* __restrict__ b2, float* __restrict__ out)
{
    __shared__ float2 Aw[HID];       // (-L2E*w_var, -L2E*w_fix) for this block's axis
    __shared__ float2 Bp[HID];       // (softplus(W2), -L2E*b1)
    __shared__ float  b2s;
    __shared__ float  tab[NR][NC];   // tab[j_uf][i_u], 8 KiB

    const int t    = threadIdx.x;
    const int o    = (blockIdx.x << 7) + (t & 127);  // 128 outputs per block
    const int axis = o >> 14;                        // block-uniform (128 | NB)
    const int b    = o & (NB - 1);

    // Issue the (independent) U loads immediately; latency hides under build.
    const float u  = U[axis ? NB + b : b];    // integration variable
    const float uf = U[axis ? b : NB + b];    // fixed coordinate

    if (t < HID) {
        const float spa = softplus_fast(W1[t]);        // weight of u0
        const float spb = softplus_fast(W1[HID + t]);  // weight of u1
        const float wv  = axis ? spb : spa;
        const float wf  = axis ? spa : spb;
        Aw[t] = make_float2(-L2E * wv, -L2E * wf);
        Bp[t] = make_float2(softplus_fast(W2[t]), -L2E * b1[t]);
    } else if (t == HID) {
        b2s = b2[0];
    }
    __syncthreads();

    // ---- build: wave w owns rows {w, w+4, ..., w+28}; lane = col 0..63 ----
    const float HX = 1.0f / (float)(NC - 1);
    const float HR = 1.0f / (float)(NR - 1);
    const int lane = t & 63;
    const int w    = t >> 6;                  // wave 0..3
    const float x  = (float)lane * HX;

    float ufr[8], z[8];
#pragma unroll
    for (int k = 0; k < 8; ++k) { ufr[k] = (float)(w + 4 * k) * HR; z[k] = 0.0f; }

#pragma unroll
    for (int h = 0; h < HID; ++h) {
        const float2 a  = Aw[h];
        const float2 bp = Bp[h];
        const float base = fmaf(x, a.x, bp.y);   // -L2E*(x*w_var + b1)
#pragma unroll
        for (int k = 0; k < 8; ++k) {
            const float tt = fmaf(ufr[k], a.y, base);
            const float e  = __builtin_amdgcn_exp2f(tt);
            z[k] = fmaf(__builtin_amdgcn_rcpf(1.0f + e), bp.x, z[k]);
        }
    }
    const float bb2 = b2s;
    const float c   = 0.5f * HX;
    float S[8];
#pragma unroll
    for (int k = 0; k < 8; ++k) {
        const float y  = softplus_fast(z[k] + bb2);
        const float yp = __shfl_up(y, 1, 64);
        S[k] = (lane >= 1) ? c * (yp + y) : 0.0f;   // trapezoid over [x_{l-1}, x_l]
    }
    // 8 independent width-64 inclusive scans
#pragma unroll
    for (int off = 1; off < 64; off <<= 1) {
#pragma unroll
        for (int k = 0; k < 8; ++k) {
            const float p = __shfl_up(S[k], off, 64);
            if (lane >= off) S[k] += p;
        }
    }
    // normalize: rcp + one Newton step (error ~ ulp^2)
#pragma unroll
    for (int k = 0; k < 8; ++k) {
        const float tot = __shfl(S[k], 63, 64);
        float inv = __builtin_amdgcn_rcpf(tot);
        inv = inv * (2.0f - tot * inv);
        tab[w + 4 * k][lane] = S[k] * inv;
    }
    __syncthreads();

    // ---- lookup: bilinear in (u, uf); threads 0..127 only ----
    if (t < 128) {
        const float fi = u  * (float)(NC - 1);
        const float fj = uf * (float)(NR - 1);
        int i = (int)fi; i = max(0, min(i, NC - 2));
        int j = (int)fj; j = max(0, min(j, NR - 2));
        const float di = fi - (float)i;
        const float dj = fj - (float)j;

        const float f00 = tab[j][i],     f01 = tab[j][i + 1];
        const float f10 = tab[j + 1][i], f11 = tab[j + 1][i + 1];

        const float a0 = fmaf(di, f01 - f00, f00);
        const float a1 = fmaf(di, f11 - f10, f10);
        float v = fmaf(dj, a1 - a0, a0);
        v = fminf(fmaxf(v, 1e-6f), 1.0f - 1e-6f);
        out[o] = v;
    }
}

extern "C" void kernel_launch(void* const* d_in, const int* in_sizes, int n_in,
                              void* d_out, int out_size, void* d_ws, size_t ws_size,
                              hipStream_t stream) {
    const float* U  = (const float*)d_in[0];
    const float* W1 = (const float*)d_in[1];
    const float* b1 = (const float*)d_in[2];
    const float* W2 = (const float*)d_in[3];
    const float* b2 = (const float*)d_in[4];
    float* out = (float*)d_out;

    hipLaunchKernelGGL(marg_kernel, dim3(256), dim3(256), 0, stream,
                       U, W1, b1, W2, b2, out);
}

// Round 7
// 11.172 us; speedup vs baseline: 1.0224x; 1.0224x over previous
//
#include <hip/hip_runtime.h>

#define NB   16384
#define HID  32
#define NR   16             // table rows (uf), 15 intervals
#define NC   64             // table cols (u),  63 intervals
#define L2E  1.44269504f    // log2(e)
#define LN2  0.69314718f

// softplus via native base-2 exp/log
__device__ __forceinline__ float softplus_fast(float x) {
    return LN2 * __builtin_amdgcn_logf(1.0f + __builtin_amdgcn_exp2f(x * L2E));
}

// One dispatch. Each block builds a 16(uf) x 64(u) normalized-CDF table in LDS
// (wave w owns rows {w, w+4, w+8, w+12}; 4 interleaved chains -> 8 trans in flight),
// then serves 128 bilinear lookups. 256 blocks -> all CUs active.
__global__ __launch_bounds__(256) void marg_kernel(
    const float* __restrict__ U,  const float* __restrict__ W1,
    const float* __restrict__ b1, const float* __restrict__ W2,
    const float* __restrict__ b2, float* __restrict__ out)
{
    __shared__ float2 Aw[HID];       // (-L2E*w_var, -L2E*w_fix) for this block's axis
    __shared__ float2 Bp[HID];       // (softplus(W2), -L2E*b1)
    __shared__ float  b2s;
    __shared__ float  tab[NR][NC];   // tab[j_uf][i_u], 4 KiB

    const int t    = threadIdx.x;
    const int o    = (blockIdx.x << 7) + (t & 127);  // 128 outputs per block
    const int axis = o >> 14;                        // block-uniform (128 | NB)
    const int b    = o & (NB - 1);

    // Issue the (independent) U loads immediately; latency hides under build.
    const float u  = U[axis ? NB + b : b];    // integration variable
    const float uf = U[axis ? b : NB + b];    // fixed coordinate

    if (t < HID) {
        const float spa = softplus_fast(W1[t]);        // weight of u0
        const float spb = softplus_fast(W1[HID + t]);  // weight of u1
        const float wv  = axis ? spb : spa;
        const float wf  = axis ? spa : spb;
        Aw[t] = make_float2(-L2E * wv, -L2E * wf);
        Bp[t] = make_float2(softplus_fast(W2[t]), -L2E * b1[t]);
    } else if (t == HID) {
        b2s = b2[0];
    }
    __syncthreads();

    // ---- build: wave w owns rows {w, w+4, w+8, w+12}; lane = col 0..63 ----
    const float HX = 1.0f / (float)(NC - 1);
    const float HR = 1.0f / (float)(NR - 1);
    const int lane = t & 63;
    const int w    = t >> 6;                  // wave 0..3
    const float x  = (float)lane * HX;

    float ufr[4], z[4];
#pragma unroll
    for (int k = 0; k < 4; ++k) { ufr[k] = (float)(w + 4 * k) * HR; z[k] = 0.0f; }

#pragma unroll
    for (int h = 0; h < HID; ++h) {
        const float2 a  = Aw[h];
        const float2 bp = Bp[h];
        const float base = fmaf(x, a.x, bp.y);   // -L2E*(x*w_var + b1)
#pragma unroll
        for (int k = 0; k < 4; ++k) {
            const float tt = fmaf(ufr[k], a.y, base);
            const float e  = __builtin_amdgcn_exp2f(tt);
            z[k] = fmaf(__builtin_amdgcn_rcpf(1.0f + e), bp.x, z[k]);
        }
    }
    const float bb2 = b2s;
    const float c   = 0.5f * HX;
    float S[4];
#pragma unroll
    for (int k = 0; k < 4; ++k) {
        const float y  = softplus_fast(z[k] + bb2);
        const float yp = __shfl_up(y, 1, 64);
        S[k] = (lane >= 1) ? c * (yp + y) : 0.0f;   // trapezoid over [x_{l-1}, x_l]
    }
    // 4 independent width-64 inclusive scans
#pragma unroll
    for (int off = 1; off < 64; off <<= 1) {
#pragma unroll
        for (int k = 0; k < 4; ++k) {
            const float p = __shfl_up(S[k], off, 64);
            if (lane >= off) S[k] += p;
        }
    }
    // normalize: rcp + one Newton step (error ~ ulp^2)
#pragma unroll
    for (int k = 0; k < 4; ++k) {
        const float tot = __shfl(S[k], 63, 64);
        float inv = __builtin_amdgcn_rcpf(tot);
        inv = inv * (2.0f - tot * inv);
        tab[w + 4 * k][lane] = S[k] * inv;
    }
    __syncthreads();

    // ---- lookup: bilinear in (u, uf); threads 0..127 only ----
    if (t < 128) {
        const float fi = u  * (float)(NC - 1);
        const float fj = uf * (float)(NR - 1);
        int i = (int)fi; i = max(0, min(i, NC - 2));
        int j = (int)fj; j = max(0, min(j, NR - 2));
        const float di = fi - (float)i;
        const float dj = fj - (float)j;

        const float f00 = tab[j][i],     f01 = tab[j][i + 1];
        const float f10 = tab[j + 1][i], f11 = tab[j + 1][i + 1];

        const float a0 = fmaf(di, f01 - f00, f00);
        const float a1 = fmaf(di, f11 - f10, f10);
        float v = fmaf(dj, a1 - a0, a0);
        v = fminf(fmaxf(v, 1e-6f), 1.0f - 1e-6f);
        out[o] = v;
    }
}

extern "C" void kernel_launch(void* const* d_in, const int* in_sizes, int n_in,
                              void* d_out, int out_size, void* d_ws, size_t ws_size,
                              hipStream_t stream) {
    const float* U  = (const float*)d_in[0];
    const float* W1 = (const float*)d_in[1];
    const float* b1 = (const float*)d_in[2];
    const float* W2 = (const float*)d_in[3];
    const float* b2 = (const float*)d_in[4];
    float* out = (float*)d_out;

    hipLaunchKernelGGL(marg_kernel, dim3(256), dim3(256), 0, stream,
                       U, W1, b1, W2, b2, out);
}

// Round 8
// 9.388 us; speedup vs baseline: 1.2167x; 1.1900x over previous
//
#include <hip/hip_runtime.h>

#define NB   16384
#define HID  32
#define NR   16             // table rows (uf), 15 intervals
#define NC   64             // table cols (u),  63 intervals
#define L2E  1.44269504f    // log2(e)
#define LN2  0.69314718f

// softplus via native base-2 exp/log
__device__ __forceinline__ float softplus_fast(float x) {
    return LN2 * __builtin_amdgcn_logf(1.0f + __builtin_amdgcn_exp2f(x * L2E));
}

// One dispatch, 128 blocks. Each block builds a 16(uf) x 64(u) normalized-CDF
// table in LDS (wave w owns rows {w,w+4,w+8,w+12}; 4 interleaved trans chains),
// then serves 256 bilinear lookups (one per thread).
//   blocks 0..63   -> axis 0 (var=u0, fix=u1), outputs 0..16383
//   blocks 64..127 -> axis 1 (var=u1, fix=u0), outputs 16384..32767
__global__ __launch_bounds__(256) void marg_kernel(
    const float* __restrict__ U,  const float* __restrict__ W1,
    const float* __restrict__ b1, const float* __restrict__ W2,
    const float* __restrict__ b2, float* __restrict__ out)
{
    __shared__ float2 Aw[HID];       // (-L2E*w_var, -L2E*w_fix) for this block's axis
    __shared__ float2 Bp[HID];       // (softplus(W2), -L2E*b1)
    __shared__ float  b2s;
    __shared__ float  tab[NR][NC];   // tab[j_uf][i_u], 4 KiB

    const int t    = threadIdx.x;
    const int o    = (blockIdx.x << 8) + t;   // output index 0..32767
    const int axis = o >> 14;                 // block-uniform (NB = 2^14)
    const int b    = o & (NB - 1);

    // Weight preamble first (critical chain feeding the build)...
    if (t < HID) {
        const float spa = softplus_fast(W1[t]);        // weight of u0
        const float spb = softplus_fast(W1[HID + t]);  // weight of u1
        const float wv  = axis ? spb : spa;
        const float wf  = axis ? spa : spb;
        Aw[t] = make_float2(-L2E * wv, -L2E * wf);
        Bp[t] = make_float2(softplus_fast(W2[t]), -L2E * b1[t]);
    } else if (t == HID) {
        b2s = b2[0];
    }
    // ...then the U loads (consumed only at the end; latency hides under build).
    const float u  = U[axis ? NB + b : b];    // integration variable
    const float uf = U[axis ? b : NB + b];    // fixed coordinate
    __syncthreads();

    // ---- build: wave w owns rows {w, w+4, w+8, w+12}; lane = col 0..63 ----
    const float HX = 1.0f / (float)(NC - 1);
    const float HR = 1.0f / (float)(NR - 1);
    const int lane = t & 63;
    const int w    = t >> 6;                  // wave 0..3
    const float x  = (float)lane * HX;

    float ufr[4], z[4];
#pragma unroll
    for (int k = 0; k < 4; ++k) { ufr[k] = (float)(w + 4 * k) * HR; z[k] = 0.0f; }

#pragma unroll
    for (int h = 0; h < HID; ++h) {
        const float2 a  = Aw[h];
        const float2 bp = Bp[h];
        const float base = fmaf(x, a.x, bp.y);   // -L2E*(x*w_var + b1)
#pragma unroll
        for (int k = 0; k < 4; ++k) {
            const float tt = fmaf(ufr[k], a.y, base);
            const float e  = __builtin_amdgcn_exp2f(tt);
            z[k] = fmaf(__builtin_amdgcn_rcpf(1.0f + e), bp.x, z[k]);
        }
    }
    const float bb2 = b2s;
    const float c   = 0.5f * HX;
    float S[4];
#pragma unroll
    for (int k = 0; k < 4; ++k) {
        const float y  = softplus_fast(z[k] + bb2);
        const float yp = __shfl_up(y, 1, 64);
        S[k] = (lane >= 1) ? c * (yp + y) : 0.0f;   // trapezoid over [x_{l-1}, x_l]
    }
    // 4 independent width-64 inclusive scans
#pragma unroll
    for (int off = 1; off < 64; off <<= 1) {
#pragma unroll
        for (int k = 0; k < 4; ++k) {
            const float p = __shfl_up(S[k], off, 64);
            if (lane >= off) S[k] += p;
        }
    }
    // normalize: rcp + one Newton step (error ~ ulp^2)
#pragma unroll
    for (int k = 0; k < 4; ++k) {
        const float tot = __shfl(S[k], 63, 64);
        float inv = __builtin_amdgcn_rcpf(tot);
        inv = inv * (2.0f - tot * inv);
        tab[w + 4 * k][lane] = S[k] * inv;
    }
    __syncthreads();

    // ---- lookup: bilinear in (u, uf); one per thread ----
    const float fi = u  * (float)(NC - 1);
    const float fj = uf * (float)(NR - 1);
    int i = (int)fi; i = max(0, min(i, NC - 2));
    int j = (int)fj; j = max(0, min(j, NR - 2));
    const float di = fi - (float)i;
    const float dj = fj - (float)j;

    const float f00 = tab[j][i],     f01 = tab[j][i + 1];
    const float f10 = tab[j + 1][i], f11 = tab[j + 1][i + 1];

    const float a0 = fmaf(di, f01 - f00, f00);
    const float a1 = fmaf(di, f11 - f10, f10);
    float v = fmaf(dj, a1 - a0, a0);
    v = fminf(fmaxf(v, 1e-6f), 1.0f - 1e-6f);
    out[o] = v;
}

extern "C" void kernel_launch(void* const* d_in, const int* in_sizes, int n_in,
                              void* d_out, int out_size, void* d_ws, size_t ws_size,
                              hipStream_t stream) {
    const float* U  = (const float*)d_in[0];
    const float* W1 = (const float*)d_in[1];
    const float* b1 = (const float*)d_in[2];
    const float* W2 = (const float*)d_in[3];
    const float* b2 = (const float*)d_in[4];
    float* out = (float*)d_out;

    hipLaunchKernelGGL(marg_kernel, dim3(128), dim3(256), 0, stream,
                       U, W1, b1, W2, b2, out);
}